// Round 14
// baseline (201.981 us; speedup 1.0000x reference)
//
#include <hip/hip_runtime.h>
#include <cmath>

#define B_  16
#define T_  1024
#define C_  512
#define NH_ 8
#define HD_ 64

#define AS1 __attribute__((address_space(1)))
#define AS3 __attribute__((address_space(3)))

// Explicit fences: do NOT trust the compiler to order LDS-DMA vs barriers.
#define FENCE_VM()   asm volatile("s_waitcnt vmcnt(0)" ::: "memory")
#define FENCE_LGKM() asm volatile("s_waitcnt lgkmcnt(0)" ::: "memory")

typedef __bf16 bf16_t;
typedef __bf16 bf16x8 __attribute__((ext_vector_type(8)));
typedef __bf16 bf16x4 __attribute__((ext_vector_type(4)));
typedef short  shortx8 __attribute__((ext_vector_type(8)));
typedef short  shortx4 __attribute__((ext_vector_type(4)));
typedef float  floatx4 __attribute__((ext_vector_type(4)));
typedef float  float4v __attribute__((ext_vector_type(4)));

// Raw transcendentals: map 1:1 onto v_exp_f32 / v_sin_f32 / v_cos_f32.
__device__ inline float fast_exp2(float x) {
#if __has_builtin(__builtin_amdgcn_exp2f)
  return __builtin_amdgcn_exp2f(x);
#else
  float r; asm("v_exp_f32 %0, %1" : "=v"(r) : "v"(x)); return r;
#endif
}
// v_sin/v_cos take REVOLUTIONS (ISA: D = sin(S0*2pi)); input pre-fract'd.
__device__ inline float hw_sin_rev(float rev) {
  float r; asm("v_sin_f32 %0, %1" : "=v"(r) : "v"(rev)); return r;
}
__device__ inline float hw_cos_rev(float rev) {
  float r; asm("v_cos_f32 %0, %1" : "=v"(r) : "v"(rev)); return r;
}

// ---- MFMA wrappers ----
//   16x16x32: A[m][k]: m=lane&15, k=(lane>>4)*8+j ; B[k][n]: n=lane&15, same k
//   16x16x16: A[m][k]: m=lane&15, k=(lane>>4)*4+j ; B[k][n]: n=lane&15, same k
//   C/D (both): col=lane&15, row=(lane>>4)*4+reg
template <typename V8>
__device__ inline auto mfma_impl(V8 a, V8 b, floatx4 c, int)
    -> decltype(__builtin_amdgcn_mfma_f32_16x16x32_bf16(a, b, c, 0, 0, 0)) {
  return __builtin_amdgcn_mfma_f32_16x16x32_bf16(a, b, c, 0, 0, 0);
}
template <typename V8>
__device__ inline floatx4 mfma_impl(V8 a, V8 b, floatx4 c, long) {
  return __builtin_amdgcn_mfma_f32_16x16x32_bf16(
      __builtin_bit_cast(shortx8, a), __builtin_bit_cast(shortx8, b), c, 0, 0, 0);
}
__device__ inline floatx4 mfma_bf16(bf16x8 a, bf16x8 b, floatx4 c) {
  return mfma_impl(a, b, c, 0);
}

// K=16 bf16 MFMA (gfx90a-era "1k" builtin, still present on gfx950).
__device__ inline floatx4 mfma16_bf16(bf16x4 a, bf16x4 b, floatx4 c) {
#if __has_builtin(__builtin_amdgcn_mfma_f32_16x16x16bf16_1k)
  return __builtin_amdgcn_mfma_f32_16x16x16bf16_1k(
      __builtin_bit_cast(shortx4, a), __builtin_bit_cast(shortx4, b), c, 0, 0, 0);
#else
  floatx4 d;
  asm("v_mfma_f32_16x16x16_bf16 %0, %1, %2, %3"
      : "=v"(d) : "v"(a), "v"(b), "0"(c));
  return d;
#endif
}

// ---- prep: transpose_x (z<16, VECTORIZED) + weight convert (z==16) ----
__global__ void prep(const float* __restrict__ x, bf16_t* __restrict__ xt,
                     const float* __restrict__ w0, const float* __restrict__ w1,
                     const float* __restrict__ w2, const float* __restrict__ w3,
                     bf16_t* __restrict__ d0, bf16_t* __restrict__ d1,
                     bf16_t* __restrict__ d2, bf16_t* __restrict__ d3) {
  const int tx = threadIdx.x, ty = threadIdx.y;   // block (32,8)
  const int id = ty * 32 + tx;                    // 0..255
  if (blockIdx.z < 16) {
    __shared__ float tile[32][36];                // pad->row stride 144B (16B-mult)
    const int b = blockIdx.z;
    const int t0 = blockIdx.x * 32, c0 = blockIdx.y * 32;
    // load: thread -> (c_local = id>>3, t4 = id&7), one float4 along t
    const int cl = id >> 3, t4 = id & 7;
    const float4v v = *(const float4v*)(x + ((size_t)b * C_ + c0 + cl) * T_ + t0 + t4 * 4);
    *(float4v*)&tile[cl][t4 * 4] = v;
    __syncthreads();
    // store: thread -> (t_local = id>>3, c4 = (id&7)*4), bf16x4 along c
    const int tl = id >> 3, c4 = (id & 7) * 4;
    bf16x4 pk;
#pragma unroll
    for (int j = 0; j < 4; j++) pk[j] = (bf16_t)tile[c4 + j][tl];
    *(bf16x4*)(xt + ((size_t)b * T_ + t0 + tl) * C_ + c0 + c4) = pk;
  } else {
    // 512 blocks (x:32, y:16) x 256 threads x 8 elems = 4 x 512x512 floats
    const float* s[4] = {w0, w1, w2, w3};
    bf16_t* d[4] = {d0, d1, d2, d3};
    const int idx = (blockIdx.y * 32 + blockIdx.x) * 256 + id;
    const int e0 = idx * 8;
    const int which = e0 >> 18;          // 262144 elems per matrix
    const int off = e0 & 262143;
    const float4v f0 = *(const float4v*)(s[which] + off);
    const float4v f1 = *(const float4v*)(s[which] + off + 4);
    bf16x8 o;
#pragma unroll
    for (int e = 0; e < 4; e++) { o[e] = (bf16_t)f0[e]; o[4 + e] = (bf16_t)f1[e]; }
    *(bf16x8*)(d[which] + off) = o;
  }
}

// ---- fused Q/K/V projection GEMM + bias + RoPE (round-6 proven version) ----
// Triple-buffered LDS staging, distance-2 prefetch, vmcnt(4) publish-certify.
__global__ __launch_bounds__(256) void qkv_gemm(
    const bf16_t* __restrict__ Wq, const bf16_t* __restrict__ Wk, const bf16_t* __restrict__ Wv,
    const float* __restrict__ bq, const float* __restrict__ bk, const float* __restrict__ bv,
    const bf16_t* __restrict__ xt,
    bf16_t* __restrict__ qo, bf16_t* __restrict__ ko, bf16_t* __restrict__ vo) {
  const int which = blockIdx.z % 3;
  const int b = blockIdx.z / 3;
  const bf16_t* W = which == 0 ? Wq : (which == 1 ? Wk : Wv);
  const float* bias = which == 0 ? bq : (which == 1 ? bk : bv);
  const int wave = threadIdx.x >> 6, lane = threadIdx.x & 63;
  const int col = lane & 15, quad = lane >> 4;
  const int MbB = blockIdx.y * 128, NbB = blockIdx.x * 128;
  const int Mw = (wave >> 1) * 64, Nw = (wave & 1) * 64;
  const bf16_t* xb = xt + (size_t)b * T_ * C_;

  __shared__ bf16_t As[3][128 * 32];
  __shared__ bf16_t Bs[3][128 * 32];

  // stage one 128x32 tile pair: 4 DMA insts per wave per k-step
  auto stageKV = [&](int i) {
    const int k0 = i * 32, buf = i % 3;
#pragma unroll
    for (int c = 0; c < 2; c++) {
      const int j = wave * 128 + c * 64 + lane;
      __builtin_amdgcn_global_load_lds(
          (const AS1 void*)(W + (MbB + (j >> 2)) * C_ + k0 + (j & 3) * 8),
          (AS3 void*)((char*)&As[buf][0] + wave * 2048 + c * 1024), 16, 0, 0);
    }
#pragma unroll
    for (int c = 0; c < 2; c++) {
      const int j = wave * 128 + c * 64 + lane;
      __builtin_amdgcn_global_load_lds(
          (const AS1 void*)(xb + (NbB + (j >> 2)) * C_ + k0 + (j & 3) * 8),
          (AS3 void*)((char*)&Bs[buf][0] + wave * 2048 + c * 1024), 16, 0, 0);
    }
  };

  floatx4 acc[4][4] = {};
  stageKV(0);
  stageKV(1);
  asm volatile("s_waitcnt vmcnt(4)\ns_barrier" ::: "memory");  // tile0 certified
  for (int i = 0; i < 16; i++) {
    if (i + 2 < 16) stageKV(i + 2);  // distance-2 prefetch
    const bf16_t* a = &As[i % 3][0];
    const bf16_t* bb = &Bs[i % 3][0];
    bf16x8 af[4], bfr[4];
#pragma unroll
    for (int mi = 0; mi < 4; mi++)
      af[mi] = *(const bf16x8*)(a + (Mw + mi * 16 + col) * 32 + quad * 8);
#pragma unroll
    for (int ni = 0; ni < 4; ni++)
      bfr[ni] = *(const bf16x8*)(bb + (Nw + ni * 16 + col) * 32 + quad * 8);
#pragma unroll
    for (int mi = 0; mi < 4; mi++)
#pragma unroll
      for (int ni = 0; ni < 4; ni++)
        acc[mi][ni] = mfma_bf16(af[mi], bfr[ni], acc[mi][ni]);
    // certify tile i+1 (oldest 4 DMA); leave tile i+2's 4 in flight.
    if (i < 14) {
      asm volatile("s_waitcnt vmcnt(4)\ns_barrier" ::: "memory");
    } else if (i == 14) {
      asm volatile("s_waitcnt vmcnt(0)\ns_barrier" ::: "memory");
    }
  }

  const int Mb = MbB + Mw, Nb = NbB + Nw;
#pragma unroll
  for (int mi = 0; mi < 4; mi++)
#pragma unroll
    for (int r = 0; r < 4; r++) {
      const float bval = bias[Mb + mi * 16 + quad * 4 + r];
#pragma unroll
      for (int ni = 0; ni < 4; ni++) acc[mi][ni][r] += bval;
    }

  const int h = Mb >> 6;
  if (which < 2) {
    // RoPE via HW sin/cos in revolutions:
    // theta_rev = 10000^(-dd/16) / (2pi) = exp2(-dd*log2(1e4)/16 - log2(2pi))
#pragma unroll
    for (int ni = 0; ni < 4; ni++) {
      const int t = Nb + ni * 16 + col;
#pragma unroll
      for (int r = 0; r < 4; r++) {
        const int dd = quad * 4 + r;
        const float theta_rev =
            fast_exp2(-(float)dd * 0.83048202372184059f - 2.6514961294723187f);
        float rev = (float)t * theta_rev;
        rev = rev - floorf(rev);
        const float sn = hw_sin_rev(rev), cs = hw_cos_rev(rev);
        const float a0 = acc[0][ni][r], a1 = acc[1][ni][r];
        acc[0][ni][r] = a0 * cs - a1 * sn;
        acc[1][ni][r] = a1 * cs + a0 * sn;
      }
    }
    bf16_t* out = which == 0 ? qo : ko;
#pragma unroll
    for (int mi = 0; mi < 4; mi++) {
      const int d0 = mi * 16 + quad * 4;
#pragma unroll
      for (int ni = 0; ni < 4; ni++) {
        const int t = Nb + ni * 16 + col;
        bf16x4 pk;
#pragma unroll
        for (int r = 0; r < 4; r++) pk[r] = (bf16_t)acc[mi][ni][r];
        *(bf16x4*)(out + ((size_t)(b * NH_ + h) * T_ + t) * HD_ + d0) = pk;
      }
    }
  } else {
#pragma unroll
    for (int mi = 0; mi < 4; mi++)
#pragma unroll
      for (int ni = 0; ni < 4; ni++) {
        const int t = Nb + ni * 16 + col;
#pragma unroll
        for (int r = 0; r < 4; r++) {
          const int d = mi * 16 + quad * 4 + r;
          vo[((size_t)(b * NH_ + h) * HD_ + d) * T_ + t] = (bf16_t)acc[mi][ni][r];
        }
      }
  }
}

// ---- attention v8: v6 frozen body/sync + ones-trick row-sums ----
// l[q] via mfma16(p4, ones, lacc): moves 32 v_add_f32/iter off the busiest
// pipe (VALU 45%) onto MFMA (40%), and D-layout (row=quad*4+r) matches oacc
// exactly -> epilogue needs ZERO cross-lane shuffles. Pattern proven in v1
// (round 1 passed with ones-MFMA row-sums); A-operand layout proven by the
// working PV call (A[m=col][k=quad*4+j] = P^T).
__global__ __launch_bounds__(512, 4) void attn_kernel(
    const bf16_t* __restrict__ qb, const bf16_t* __restrict__ kb,
    const bf16_t* __restrict__ vtb, bf16_t* __restrict__ ob) {
  const int id = blockIdx.x;
  const int bh = id & 127;          // id%8 == bh%8 -> same XCD for all q-tiles
  const int qt = id >> 7;           // 0..3
  const int tid = threadIdx.x;
  const int wave = tid >> 6, lane = tid & 63;
  const int col = lane & 15, quad = lane >> 4;
  const int tq0 = qt * 256 + wave * 32;

  const bf16_t* Q = qb + (size_t)bh * T_ * HD_;
  const bf16_t* K = kb + (size_t)bh * T_ * HD_;
  const bf16_t* VT = vtb + (size_t)bh * HD_ * T_;

  __shared__ bf16_t kvs[3][2][4096];   // [buf][K=0/V=1][64x64, XOR-swizzled]

  // stage one 64x64 tile (8KB = 512 chunks of 16B): 1 inst per thread.
  auto stage = [&](const char* gRowBase, int rowStrideB, bf16_t* dst) {
    const int r = tid >> 3, ck = tid & 7;   // chunk j = tid
    const char* src = gRowBase + r * rowStrideB + ((ck ^ (r & 7)) << 4);
    __builtin_amdgcn_global_load_lds(
        (const AS1 void*)src,
        (AS3 void*)((char*)dst + wave * 1024), 16, 0, 0);
  };
  auto stageKV = [&](int tk0, int buf) {
    stage((const char*)(K + (size_t)tk0 * HD_), HD_ * 2, &kvs[buf][0][0]);
    stage((const char*)VT + (size_t)tk0 * 2, T_ * 2, &kvs[buf][1][0]);
  };
  auto frag = [&](const bf16_t* base, int R, int cg) -> bf16x8 {
    return *(const bf16x8*)(base + R * 64 + ((cg ^ (R & 7)) << 3));
  };

  floatx4 oacc[2][4] = {};
  floatx4 lacc[2] = {};                // l[q=tq0+g*16+quad*4+r] via ones-MFMA
  const float CEXP = 0.18033688011112042f;  // 0.125 * log2(e)

  bf16x4 ones4;
#pragma unroll
  for (int e = 0; e < 4; e++) ones4[e] = (bf16_t)1.0f;

  // prologue: stage tiles 0,1; load Q pre-scaled; vmcnt(0); barrier.
  stageKV(0, 0);
  stageKV(64, 1);
  bf16x8 qf[2][2];  // [row-group g][k-chunk]
#pragma unroll
  for (int g = 0; g < 2; g++)
#pragma unroll
    for (int kk = 0; kk < 2; kk++) {
      bf16x8 raw = *(const bf16x8*)(Q + (tq0 + g * 16 + col) * HD_ + kk * 32 + quad * 8);
#pragma unroll
      for (int e = 0; e < 8; e++) qf[g][kk][e] = (bf16_t)((float)raw[e] * CEXP);
    }
  FENCE_VM();
  __syncthreads();

  for (int it = 0; it < 16; it++) {
    const int buf = it % 3;
    if (it + 2 < 16) stageKV((it + 2) * 64, (it + 2) % 3);  // distance-2 prefetch
    const bf16_t* kt = &kvs[buf][0][0];
    const bf16_t* vt = &kvs[buf][1][0];

    // QK^T, operands SWAPPED: s[g][ni][r] = S[key=ni*16+quad*4+r][q=tq0+g*16+col]
    floatx4 s[2][4] = {};
#pragma unroll
    for (int ni = 0; ni < 4; ni++)
#pragma unroll
      for (int kk = 0; kk < 2; kk++) {
        const bf16x8 kf = frag(kt, ni * 16 + col, kk * 4 + quad);
        s[0][ni] = mfma_bf16(kf, qf[0][kk], s[0][ni]);
        s[1][ni] = mfma_bf16(kf, qf[1][kk], s[1][ni]);
      }

    // exp in-register; pack P to bf16x4 (row-sum moved to ones-MFMA below).
    bf16x4 p4[2][4];
#pragma unroll
    for (int g = 0; g < 2; g++)
#pragma unroll
      for (int ni = 0; ni < 4; ni++)
#pragma unroll
        for (int r = 0; r < 4; r++)
          p4[g][ni][r] = (bf16_t)fast_exp2(s[g][ni][r]);

    // l[q] += sum_key P: D[m=q][n]=const across n; reg r = q=quad*4+r.
#pragma unroll
    for (int g = 0; g < 2; g++)
#pragma unroll
      for (int ni = 0; ni < 4; ni++)
        lacc[g] = mfma16_bf16(p4[g][ni], ones4, lacc[g]);

    // PV via K=16 MFMA: A=p4 (regs), B=VT b64 frag (keys ni*16+quad*4+0..3).
#pragma unroll
    for (int nd = 0; nd < 4; nd++) {
      const int R = nd * 16 + col;
      bf16x4 v4[4];
#pragma unroll
      for (int ni = 0; ni < 4; ni++) {
        const int c8 = ni * 2 + (quad >> 1);
        v4[ni] = *(const bf16x4*)(vt + R * 64 + ((c8 ^ (R & 7)) << 3) + (quad & 1) * 4);
      }
#pragma unroll
      for (int ni = 0; ni < 4; ni++) {
        oacc[0][nd] = mfma16_bf16(p4[0][ni], v4[ni], oacc[0][nd]);
        oacc[1][nd] = mfma16_bf16(p4[1][ni], v4[ni], oacc[1][nd]);
      }
    }

    // certify tile it+1 (oldest 2 DMA); leave tile it+2's 2 in flight.
    if (it < 14) {
      asm volatile("s_waitcnt vmcnt(2)\ns_barrier" ::: "memory");
    } else if (it == 14) {
      asm volatile("s_waitcnt vmcnt(0)\ns_barrier" ::: "memory");
    }
  }

  // lacc[g][r] = l[q=tq0+g*16+quad*4+r] — same row layout as oacc: no shuffles.
  float linv[2][4];
#pragma unroll
  for (int g = 0; g < 2; g++)
#pragma unroll
    for (int r = 0; r < 4; r++)
      linv[g][r] = 1.0f / lacc[g][r];
#pragma unroll
  for (int g = 0; g < 2; g++)
#pragma unroll
    for (int nd = 0; nd < 4; nd++)
#pragma unroll
      for (int r = 0; r < 4; r++) {
        const float v = oacc[g][nd][r] * linv[g][r];
        ob[((size_t)bh * T_ + tq0 + g * 16 + quad * 4 + r) * HD_ + nd * 16 + col] = (bf16_t)v;
      }
}

// ---- output projection: frozen triple-buffered distance-2 skeleton ----
__global__ __launch_bounds__(256) void out_gemm(
    const bf16_t* __restrict__ W, const float* __restrict__ bias,
    const bf16_t* __restrict__ ao, float* __restrict__ y) {
  const int b = blockIdx.z;
  const int wave = threadIdx.x >> 6, lane = threadIdx.x & 63;
  const int col = lane & 15, quad = lane >> 4;
  const int MbB = blockIdx.y * 128, NbB = blockIdx.x * 128;
  const int Mw = (wave >> 1) * 64, Nw = (wave & 1) * 64;
  const bf16_t* ab = ao + (size_t)b * NH_ * T_ * HD_;

  __shared__ bf16_t As[3][128 * 32];
  __shared__ bf16_t Bs[3][128 * 32];

  auto stageKV = [&](int i) {
    const int k0 = i * 32, buf = i % 3;
#pragma unroll
    for (int c = 0; c < 2; c++) {
      const int j = wave * 128 + c * 64 + lane;
      __builtin_amdgcn_global_load_lds(
          (const AS1 void*)(W + (MbB + (j >> 2)) * C_ + k0 + (j & 3) * 8),
          (AS3 void*)((char*)&As[buf][0] + wave * 2048 + c * 1024), 16, 0, 0);
    }
#pragma unroll
    for (int c = 0; c < 2; c++) {
      const int j = wave * 128 + c * 64 + lane;
      const int kg = k0 + (j & 3) * 8;   // global k; 8-chunk stays in one head
      __builtin_amdgcn_global_load_lds(
          (const AS1 void*)(ab + ((size_t)(kg >> 6) * T_ + NbB + (j >> 2)) * HD_ + (kg & 63)),
          (AS3 void*)((char*)&Bs[buf][0] + wave * 2048 + c * 1024), 16, 0, 0);
    }
  };

  floatx4 acc[4][4] = {};
  stageKV(0);
  stageKV(1);
  asm volatile("s_waitcnt vmcnt(4)\ns_barrier" ::: "memory");
  for (int i = 0; i < 16; i++) {
    if (i + 2 < 16) stageKV(i + 2);
    const bf16_t* a = &As[i % 3][0];
    const bf16_t* bb = &Bs[i % 3][0];
    bf16x8 af[4], bfr[4];
#pragma unroll
    for (int mi = 0; mi < 4; mi++)
      af[mi] = *(const bf16x8*)(a + (Mw + mi * 16 + col) * 32 + quad * 8);
#pragma unroll
    for (int ni = 0; ni < 4; ni++)
      bfr[ni] = *(const bf16x8*)(bb + (Nw + ni * 16 + col) * 32 + quad * 8);
#pragma unroll
    for (int mi = 0; mi < 4; mi++)
#pragma unroll
      for (int ni = 0; ni < 4; ni++)
        acc[mi][ni] = mfma_bf16(af[mi], bfr[ni], acc[mi][ni]);
    if (i < 14) {
      asm volatile("s_waitcnt vmcnt(4)\ns_barrier" ::: "memory");
    } else if (i == 14) {
      asm volatile("s_waitcnt vmcnt(0)\ns_barrier" ::: "memory");
    }
  }

  const int Mb = MbB + Mw, Nb = NbB + Nw;
#pragma unroll
  for (int mi = 0; mi < 4; mi++)
#pragma unroll
    for (int r = 0; r < 4; r++) {
      const int o = Mb + mi * 16 + quad * 4 + r;
      const float bval = bias[o];
#pragma unroll
      for (int ni = 0; ni < 4; ni++) {
        const int t = Nb + ni * 16 + col;
        y[((size_t)b * C_ + o) * T_ + t] = acc[mi][ni][r] + bval;
      }
    }
}

extern "C" void kernel_launch(void* const* d_in, const int* in_sizes, int n_in,
                              void* d_out, int out_size, void* d_ws, size_t ws_size,
                              hipStream_t stream) {
  const float* x  = (const float*)d_in[0];
  const float* Wq = (const float*)d_in[1];
  const float* bq = (const float*)d_in[2];
  const float* Wk = (const float*)d_in[3];
  const float* bk = (const float*)d_in[4];
  const float* Wv = (const float*)d_in[5];
  const float* bv = (const float*)d_in[6];
  const float* Wo = (const float*)d_in[7];
  const float* bo = (const float*)d_in[8];
  float* y = (float*)d_out;

  char* ws = (char*)d_ws;
  const size_t WB = (size_t)C_ * C_ * 2;
  const size_t XB = (size_t)B_ * T_ * C_ * 2;
  bf16_t* wqb = (bf16_t*)(ws + 0 * WB);
  bf16_t* wkb = (bf16_t*)(ws + 1 * WB);
  bf16_t* wvb = (bf16_t*)(ws + 2 * WB);
  bf16_t* wob = (bf16_t*)(ws + 3 * WB);
  bf16_t* xt  = (bf16_t*)(ws + 4 * WB);
  bf16_t* qb_ = (bf16_t*)(ws + 4 * WB + 1 * XB);
  bf16_t* kb_ = (bf16_t*)(ws + 4 * WB + 2 * XB);
  bf16_t* vtb = (bf16_t*)(ws + 4 * WB + 3 * XB);
  bf16_t* aob = xt;  // alias: x_t dead after qkv_gemm

  prep<<<dim3(T_ / 32, C_ / 32, B_ + 1), dim3(32, 8), 0, stream>>>(
      x, xt, Wq, Wk, Wv, Wo, wqb, wkb, wvb, wob);
  qkv_gemm<<<dim3(T_ / 128, C_ / 128, B_ * 3), dim3(256), 0, stream>>>(
      wqb, wkb, wvb, bq, bk, bv, xt, qb_, kb_, vtb);
  attn_kernel<<<dim3((T_ / 256) * B_ * NH_), dim3(512), 0, stream>>>(qb_, kb_, vtb, aob);
  out_gemm<<<dim3(T_ / 128, C_ / 128, B_), dim3(256), 0, stream>>>(wob, bo, aob, y);
}

// Round 15
// 194.417 us; speedup vs baseline: 1.0389x; 1.0389x over previous
//
#include <hip/hip_runtime.h>
#include <cmath>

#define B_  16
#define T_  1024
#define C_  512
#define NH_ 8
#define HD_ 64

#define AS1 __attribute__((address_space(1)))
#define AS3 __attribute__((address_space(3)))

// Explicit fences: do NOT trust the compiler to order LDS-DMA vs barriers.
#define FENCE_VM()   asm volatile("s_waitcnt vmcnt(0)" ::: "memory")
#define FENCE_LGKM() asm volatile("s_waitcnt lgkmcnt(0)" ::: "memory")

typedef __bf16 bf16_t;
typedef __bf16 bf16x8 __attribute__((ext_vector_type(8)));
typedef __bf16 bf16x4 __attribute__((ext_vector_type(4)));
typedef short  shortx8 __attribute__((ext_vector_type(8)));
typedef short  shortx4 __attribute__((ext_vector_type(4)));
typedef float  floatx4 __attribute__((ext_vector_type(4)));
typedef float  float4v __attribute__((ext_vector_type(4)));

// Raw transcendentals: map 1:1 onto v_exp_f32 / v_sin_f32 / v_cos_f32.
__device__ inline float fast_exp2(float x) {
#if __has_builtin(__builtin_amdgcn_exp2f)
  return __builtin_amdgcn_exp2f(x);
#else
  float r; asm("v_exp_f32 %0, %1" : "=v"(r) : "v"(x)); return r;
#endif
}
// v_sin/v_cos take REVOLUTIONS (ISA: D = sin(S0*2pi)); input pre-fract'd.
__device__ inline float hw_sin_rev(float rev) {
  float r; asm("v_sin_f32 %0, %1" : "=v"(r) : "v"(rev)); return r;
}
__device__ inline float hw_cos_rev(float rev) {
  float r; asm("v_cos_f32 %0, %1" : "=v"(r) : "v"(rev)); return r;
}

// ---- MFMA wrappers ----
//   16x16x32: A[m][k]: m=lane&15, k=(lane>>4)*8+j ; B[k][n]: n=lane&15, same k
//   16x16x16: A[m][k]: m=lane&15, k=(lane>>4)*4+j ; B[k][n]: n=lane&15, same k
//   C/D (both): col=lane&15, row=(lane>>4)*4+reg
template <typename V8>
__device__ inline auto mfma_impl(V8 a, V8 b, floatx4 c, int)
    -> decltype(__builtin_amdgcn_mfma_f32_16x16x32_bf16(a, b, c, 0, 0, 0)) {
  return __builtin_amdgcn_mfma_f32_16x16x32_bf16(a, b, c, 0, 0, 0);
}
template <typename V8>
__device__ inline floatx4 mfma_impl(V8 a, V8 b, floatx4 c, long) {
  return __builtin_amdgcn_mfma_f32_16x16x32_bf16(
      __builtin_bit_cast(shortx8, a), __builtin_bit_cast(shortx8, b), c, 0, 0, 0);
}
__device__ inline floatx4 mfma_bf16(bf16x8 a, bf16x8 b, floatx4 c) {
  return mfma_impl(a, b, c, 0);
}

// K=16 bf16 MFMA (gfx90a-era "1k" builtin, still present on gfx950).
__device__ inline floatx4 mfma16_bf16(bf16x4 a, bf16x4 b, floatx4 c) {
#if __has_builtin(__builtin_amdgcn_mfma_f32_16x16x16bf16_1k)
  return __builtin_amdgcn_mfma_f32_16x16x16bf16_1k(
      __builtin_bit_cast(shortx4, a), __builtin_bit_cast(shortx4, b), c, 0, 0, 0);
#else
  floatx4 d;
  asm("v_mfma_f32_16x16x16_bf16 %0, %1, %2, %3"
      : "=v"(d) : "v"(a), "v"(b), "0"(c));
  return d;
#endif
}

// ---- prep: transpose_x (z<16, VECTORIZED) + weight convert (z==16) ----
__global__ void prep(const float* __restrict__ x, bf16_t* __restrict__ xt,
                     const float* __restrict__ w0, const float* __restrict__ w1,
                     const float* __restrict__ w2, const float* __restrict__ w3,
                     bf16_t* __restrict__ d0, bf16_t* __restrict__ d1,
                     bf16_t* __restrict__ d2, bf16_t* __restrict__ d3) {
  const int tx = threadIdx.x, ty = threadIdx.y;   // block (32,8)
  const int id = ty * 32 + tx;                    // 0..255
  if (blockIdx.z < 16) {
    __shared__ float tile[32][36];                // pad->row stride 144B (16B-mult)
    const int b = blockIdx.z;
    const int t0 = blockIdx.x * 32, c0 = blockIdx.y * 32;
    // load: thread -> (c_local = id>>3, t4 = id&7), one float4 along t
    const int cl = id >> 3, t4 = id & 7;
    const float4v v = *(const float4v*)(x + ((size_t)b * C_ + c0 + cl) * T_ + t0 + t4 * 4);
    *(float4v*)&tile[cl][t4 * 4] = v;
    __syncthreads();
    // store: thread -> (t_local = id>>3, c4 = (id&7)*4), bf16x4 along c
    const int tl = id >> 3, c4 = (id & 7) * 4;
    bf16x4 pk;
#pragma unroll
    for (int j = 0; j < 4; j++) pk[j] = (bf16_t)tile[c4 + j][tl];
    *(bf16x4*)(xt + ((size_t)b * T_ + t0 + tl) * C_ + c0 + c4) = pk;
  } else {
    // 512 blocks (x:32, y:16) x 256 threads x 8 elems = 4 x 512x512 floats
    const float* s[4] = {w0, w1, w2, w3};
    bf16_t* d[4] = {d0, d1, d2, d3};
    const int idx = (blockIdx.y * 32 + blockIdx.x) * 256 + id;
    const int e0 = idx * 8;
    const int which = e0 >> 18;          // 262144 elems per matrix
    const int off = e0 & 262143;
    const float4v f0 = *(const float4v*)(s[which] + off);
    const float4v f1 = *(const float4v*)(s[which] + off + 4);
    bf16x8 o;
#pragma unroll
    for (int e = 0; e < 4; e++) { o[e] = (bf16_t)f0[e]; o[4 + e] = (bf16_t)f1[e]; }
    *(bf16x8*)(d[which] + off) = o;
  }
}

// ---- fused Q/K/V projection GEMM + bias + RoPE (round-6 proven version) ----
// Triple-buffered LDS staging, distance-2 prefetch, vmcnt(4) publish-certify.
__global__ __launch_bounds__(256) void qkv_gemm(
    const bf16_t* __restrict__ Wq, const bf16_t* __restrict__ Wk, const bf16_t* __restrict__ Wv,
    const float* __restrict__ bq, const float* __restrict__ bk, const float* __restrict__ bv,
    const bf16_t* __restrict__ xt,
    bf16_t* __restrict__ qo, bf16_t* __restrict__ ko, bf16_t* __restrict__ vo) {
  const int which = blockIdx.z % 3;
  const int b = blockIdx.z / 3;
  const bf16_t* W = which == 0 ? Wq : (which == 1 ? Wk : Wv);
  const float* bias = which == 0 ? bq : (which == 1 ? bk : bv);
  const int wave = threadIdx.x >> 6, lane = threadIdx.x & 63;
  const int col = lane & 15, quad = lane >> 4;
  const int MbB = blockIdx.y * 128, NbB = blockIdx.x * 128;
  const int Mw = (wave >> 1) * 64, Nw = (wave & 1) * 64;
  const bf16_t* xb = xt + (size_t)b * T_ * C_;

  __shared__ bf16_t As[3][128 * 32];
  __shared__ bf16_t Bs[3][128 * 32];

  // stage one 128x32 tile pair: 4 DMA insts per wave per k-step
  auto stageKV = [&](int i) {
    const int k0 = i * 32, buf = i % 3;
#pragma unroll
    for (int c = 0; c < 2; c++) {
      const int j = wave * 128 + c * 64 + lane;
      __builtin_amdgcn_global_load_lds(
          (const AS1 void*)(W + (MbB + (j >> 2)) * C_ + k0 + (j & 3) * 8),
          (AS3 void*)((char*)&As[buf][0] + wave * 2048 + c * 1024), 16, 0, 0);
    }
#pragma unroll
    for (int c = 0; c < 2; c++) {
      const int j = wave * 128 + c * 64 + lane;
      __builtin_amdgcn_global_load_lds(
          (const AS1 void*)(xb + (NbB + (j >> 2)) * C_ + k0 + (j & 3) * 8),
          (AS3 void*)((char*)&Bs[buf][0] + wave * 2048 + c * 1024), 16, 0, 0);
    }
  };

  floatx4 acc[4][4] = {};
  stageKV(0);
  stageKV(1);
  asm volatile("s_waitcnt vmcnt(4)\ns_barrier" ::: "memory");  // tile0 certified
  for (int i = 0; i < 16; i++) {
    if (i + 2 < 16) stageKV(i + 2);  // distance-2 prefetch
    const bf16_t* a = &As[i % 3][0];
    const bf16_t* bb = &Bs[i % 3][0];
    bf16x8 af[4], bfr[4];
#pragma unroll
    for (int mi = 0; mi < 4; mi++)
      af[mi] = *(const bf16x8*)(a + (Mw + mi * 16 + col) * 32 + quad * 8);
#pragma unroll
    for (int ni = 0; ni < 4; ni++)
      bfr[ni] = *(const bf16x8*)(bb + (Nw + ni * 16 + col) * 32 + quad * 8);
#pragma unroll
    for (int mi = 0; mi < 4; mi++)
#pragma unroll
      for (int ni = 0; ni < 4; ni++)
        acc[mi][ni] = mfma_bf16(af[mi], bfr[ni], acc[mi][ni]);
    // certify tile i+1 (oldest 4 DMA); leave tile i+2's 4 in flight.
    if (i < 14) {
      asm volatile("s_waitcnt vmcnt(4)\ns_barrier" ::: "memory");
    } else if (i == 14) {
      asm volatile("s_waitcnt vmcnt(0)\ns_barrier" ::: "memory");
    }
  }

  const int Mb = MbB + Mw, Nb = NbB + Nw;
#pragma unroll
  for (int mi = 0; mi < 4; mi++)
#pragma unroll
    for (int r = 0; r < 4; r++) {
      const float bval = bias[Mb + mi * 16 + quad * 4 + r];
#pragma unroll
      for (int ni = 0; ni < 4; ni++) acc[mi][ni][r] += bval;
    }

  const int h = Mb >> 6;
  if (which < 2) {
    // RoPE via HW sin/cos in revolutions:
    // theta_rev = 10000^(-dd/16) / (2pi) = exp2(-dd*log2(1e4)/16 - log2(2pi))
#pragma unroll
    for (int ni = 0; ni < 4; ni++) {
      const int t = Nb + ni * 16 + col;
#pragma unroll
      for (int r = 0; r < 4; r++) {
        const int dd = quad * 4 + r;
        const float theta_rev =
            fast_exp2(-(float)dd * 0.83048202372184059f - 2.6514961294723187f);
        float rev = (float)t * theta_rev;
        rev = rev - floorf(rev);
        const float sn = hw_sin_rev(rev), cs = hw_cos_rev(rev);
        const float a0 = acc[0][ni][r], a1 = acc[1][ni][r];
        acc[0][ni][r] = a0 * cs - a1 * sn;
        acc[1][ni][r] = a1 * cs + a0 * sn;
      }
    }
    bf16_t* out = which == 0 ? qo : ko;
#pragma unroll
    for (int mi = 0; mi < 4; mi++) {
      const int d0 = mi * 16 + quad * 4;
#pragma unroll
      for (int ni = 0; ni < 4; ni++) {
        const int t = Nb + ni * 16 + col;
        bf16x4 pk;
#pragma unroll
        for (int r = 0; r < 4; r++) pk[r] = (bf16_t)acc[mi][ni][r];
        *(bf16x4*)(out + ((size_t)(b * NH_ + h) * T_ + t) * HD_ + d0) = pk;
      }
    }
  } else {
#pragma unroll
    for (int mi = 0; mi < 4; mi++)
#pragma unroll
      for (int ni = 0; ni < 4; ni++) {
        const int t = Nb + ni * 16 + col;
#pragma unroll
        for (int r = 0; r < 4; r++) {
          const int d = mi * 16 + quad * 4 + r;
          vo[((size_t)(b * NH_ + h) * HD_ + d) * T_ + t] = (bf16_t)acc[mi][ni][r];
        }
      }
  }
}

// ---- attention v6 (FINAL: round-13 session-best, byte-exact) ----
// v2 compute body; triple-buffer, distance-2 prefetch, vmcnt(2) certify.
// Rejected by A/B: setprio (+22% regress), ones-trick row-sums (+3% regress),
// hoisted-pointer restructure (race), occupancy split (duplicated staging).
__global__ __launch_bounds__(512, 4) void attn_kernel(
    const bf16_t* __restrict__ qb, const bf16_t* __restrict__ kb,
    const bf16_t* __restrict__ vtb, bf16_t* __restrict__ ob) {
  const int id = blockIdx.x;
  const int bh = id & 127;          // id%8 == bh%8 -> same XCD for all q-tiles
  const int qt = id >> 7;           // 0..3
  const int tid = threadIdx.x;
  const int wave = tid >> 6, lane = tid & 63;
  const int col = lane & 15, quad = lane >> 4;
  const int tq0 = qt * 256 + wave * 32;

  const bf16_t* Q = qb + (size_t)bh * T_ * HD_;
  const bf16_t* K = kb + (size_t)bh * T_ * HD_;
  const bf16_t* VT = vtb + (size_t)bh * HD_ * T_;

  __shared__ bf16_t kvs[3][2][4096];   // [buf][K=0/V=1][64x64, XOR-swizzled]

  // stage one 64x64 tile (8KB = 512 chunks of 16B): 1 inst per thread.
  auto stage = [&](const char* gRowBase, int rowStrideB, bf16_t* dst) {
    const int r = tid >> 3, ck = tid & 7;   // chunk j = tid
    const char* src = gRowBase + r * rowStrideB + ((ck ^ (r & 7)) << 4);
    __builtin_amdgcn_global_load_lds(
        (const AS1 void*)src,
        (AS3 void*)((char*)dst + wave * 1024), 16, 0, 0);
  };
  auto stageKV = [&](int tk0, int buf) {
    stage((const char*)(K + (size_t)tk0 * HD_), HD_ * 2, &kvs[buf][0][0]);
    stage((const char*)VT + (size_t)tk0 * 2, T_ * 2, &kvs[buf][1][0]);
  };
  auto frag = [&](const bf16_t* base, int R, int cg) -> bf16x8 {
    return *(const bf16x8*)(base + R * 64 + ((cg ^ (R & 7)) << 3));
  };

  floatx4 oacc[2][4] = {};
  floatx4 lacc4[2] = {};               // per-lane f32 row-sum partials (q=col)
  const float CEXP = 0.18033688011112042f;  // 0.125 * log2(e)

  // prologue: stage tiles 0,1; load Q pre-scaled; vmcnt(0); barrier.
  stageKV(0, 0);
  stageKV(64, 1);
  bf16x8 qf[2][2];  // [row-group g][k-chunk]
#pragma unroll
  for (int g = 0; g < 2; g++)
#pragma unroll
    for (int kk = 0; kk < 2; kk++) {
      bf16x8 raw = *(const bf16x8*)(Q + (tq0 + g * 16 + col) * HD_ + kk * 32 + quad * 8);
#pragma unroll
      for (int e = 0; e < 8; e++) qf[g][kk][e] = (bf16_t)((float)raw[e] * CEXP);
    }
  FENCE_VM();
  __syncthreads();

  for (int it = 0; it < 16; it++) {
    const int buf = it % 3;
    if (it + 2 < 16) stageKV((it + 2) * 64, (it + 2) % 3);  // distance-2 prefetch
    const bf16_t* kt = &kvs[buf][0][0];
    const bf16_t* vt = &kvs[buf][1][0];

    // QK^T, operands SWAPPED: s[g][ni][r] = S[key=ni*16+quad*4+r][q=tq0+g*16+col]
    floatx4 s[2][4] = {};
#pragma unroll
    for (int ni = 0; ni < 4; ni++)
#pragma unroll
      for (int kk = 0; kk < 2; kk++) {
        const bf16x8 kf = frag(kt, ni * 16 + col, kk * 4 + quad);
        s[0][ni] = mfma_bf16(kf, qf[0][kk], s[0][ni]);
        s[1][ni] = mfma_bf16(kf, qf[1][kk], s[1][ni]);
      }

    // exp in-register; accumulate f32 row-sum partials; pack P to bf16x4.
    bf16x4 p4[2][4];
#pragma unroll
    for (int g = 0; g < 2; g++)
#pragma unroll
      for (int ni = 0; ni < 4; ni++)
#pragma unroll
        for (int r = 0; r < 4; r++) {
          const float pv = fast_exp2(s[g][ni][r]);
          lacc4[g][r] += pv;
          p4[g][ni][r] = (bf16_t)pv;
        }

    // PV via K=16 MFMA: A=p4 (regs), B=VT b64 frag (keys ni*16+quad*4+0..3).
#pragma unroll
    for (int nd = 0; nd < 4; nd++) {
      const int R = nd * 16 + col;
      bf16x4 v4[4];
#pragma unroll
      for (int ni = 0; ni < 4; ni++) {
        const int c8 = ni * 2 + (quad >> 1);
        v4[ni] = *(const bf16x4*)(vt + R * 64 + ((c8 ^ (R & 7)) << 3) + (quad & 1) * 4);
      }
#pragma unroll
      for (int ni = 0; ni < 4; ni++) {
        oacc[0][nd] = mfma16_bf16(p4[0][ni], v4[ni], oacc[0][nd]);
        oacc[1][nd] = mfma16_bf16(p4[1][ni], v4[ni], oacc[1][nd]);
      }
    }

    // certify tile it+1 (oldest 2 DMA); leave tile it+2's 2 in flight.
    if (it < 14) {
      asm volatile("s_waitcnt vmcnt(2)\ns_barrier" ::: "memory");
    } else if (it == 14) {
      asm volatile("s_waitcnt vmcnt(0)\ns_barrier" ::: "memory");
    }
  }

  // l[q=col]: sum r-partials, then across quads (xor 16, 32).
  float lrow[2];
#pragma unroll
  for (int g = 0; g < 2; g++) {
    lrow[g] = lacc4[g][0] + lacc4[g][1] + lacc4[g][2] + lacc4[g][3];
    lrow[g] += __shfl_xor(lrow[g], 16, 64);
    lrow[g] += __shfl_xor(lrow[g], 32, 64);
  }
  // oacc rows are q=quad*4+r -> fetch l from lane (quad*4+r).
  float linv[2][4];
#pragma unroll
  for (int g = 0; g < 2; g++)
#pragma unroll
    for (int r = 0; r < 4; r++)
      linv[g][r] = 1.0f / __shfl(lrow[g], quad * 4 + r, 64);
#pragma unroll
  for (int g = 0; g < 2; g++)
#pragma unroll
    for (int nd = 0; nd < 4; nd++)
#pragma unroll
      for (int r = 0; r < 4; r++) {
        const float v = oacc[g][nd][r] * linv[g][r];
        ob[((size_t)bh * T_ + tq0 + g * 16 + quad * 4 + r) * HD_ + nd * 16 + col] = (bf16_t)v;
      }
}

// ---- output projection: frozen triple-buffered distance-2 skeleton ----
__global__ __launch_bounds__(256) void out_gemm(
    const bf16_t* __restrict__ W, const float* __restrict__ bias,
    const bf16_t* __restrict__ ao, float* __restrict__ y) {
  const int b = blockIdx.z;
  const int wave = threadIdx.x >> 6, lane = threadIdx.x & 63;
  const int col = lane & 15, quad = lane >> 4;
  const int MbB = blockIdx.y * 128, NbB = blockIdx.x * 128;
  const int Mw = (wave >> 1) * 64, Nw = (wave & 1) * 64;
  const bf16_t* ab = ao + (size_t)b * NH_ * T_ * HD_;

  __shared__ bf16_t As[3][128 * 32];
  __shared__ bf16_t Bs[3][128 * 32];

  auto stageKV = [&](int i) {
    const int k0 = i * 32, buf = i % 3;
#pragma unroll
    for (int c = 0; c < 2; c++) {
      const int j = wave * 128 + c * 64 + lane;
      __builtin_amdgcn_global_load_lds(
          (const AS1 void*)(W + (MbB + (j >> 2)) * C_ + k0 + (j & 3) * 8),
          (AS3 void*)((char*)&As[buf][0] + wave * 2048 + c * 1024), 16, 0, 0);
    }
#pragma unroll
    for (int c = 0; c < 2; c++) {
      const int j = wave * 128 + c * 64 + lane;
      const int kg = k0 + (j & 3) * 8;   // global k; 8-chunk stays in one head
      __builtin_amdgcn_global_load_lds(
          (const AS1 void*)(ab + ((size_t)(kg >> 6) * T_ + NbB + (j >> 2)) * HD_ + (kg & 63)),
          (AS3 void*)((char*)&Bs[buf][0] + wave * 2048 + c * 1024), 16, 0, 0);
    }
  };

  floatx4 acc[4][4] = {};
  stageKV(0);
  stageKV(1);
  asm volatile("s_waitcnt vmcnt(4)\ns_barrier" ::: "memory");
  for (int i = 0; i < 16; i++) {
    if (i + 2 < 16) stageKV(i + 2);
    const bf16_t* a = &As[i % 3][0];
    const bf16_t* bb = &Bs[i % 3][0];
    bf16x8 af[4], bfr[4];
#pragma unroll
    for (int mi = 0; mi < 4; mi++)
      af[mi] = *(const bf16x8*)(a + (Mw + mi * 16 + col) * 32 + quad * 8);
#pragma unroll
    for (int ni = 0; ni < 4; ni++)
      bfr[ni] = *(const bf16x8*)(bb + (Nw + ni * 16 + col) * 32 + quad * 8);
#pragma unroll
    for (int mi = 0; mi < 4; mi++)
#pragma unroll
      for (int ni = 0; ni < 4; ni++)
        acc[mi][ni] = mfma_bf16(af[mi], bfr[ni], acc[mi][ni]);
    if (i < 14) {
      asm volatile("s_waitcnt vmcnt(4)\ns_barrier" ::: "memory");
    } else if (i == 14) {
      asm volatile("s_waitcnt vmcnt(0)\ns_barrier" ::: "memory");
    }
  }

  const int Mb = MbB + Mw, Nb = NbB + Nw;
#pragma unroll
  for (int mi = 0; mi < 4; mi++)
#pragma unroll
    for (int r = 0; r < 4; r++) {
      const int o = Mb + mi * 16 + quad * 4 + r;
      const float bval = bias[o];
#pragma unroll
      for (int ni = 0; ni < 4; ni++) {
        const int t = Nb + ni * 16 + col;
        y[((size_t)b * C_ + o) * T_ + t] = acc[mi][ni][r] + bval;
      }
    }
}

extern "C" void kernel_launch(void* const* d_in, const int* in_sizes, int n_in,
                              void* d_out, int out_size, void* d_ws, size_t ws_size,
                              hipStream_t stream) {
  const float* x  = (const float*)d_in[0];
  const float* Wq = (const float*)d_in[1];
  const float* bq = (const float*)d_in[2];
  const float* Wk = (const float*)d_in[3];
  const float* bk = (const float*)d_in[4];
  const float* Wv = (const float*)d_in[5];
  const float* bv = (const float*)d_in[6];
  const float* Wo = (const float*)d_in[7];
  const float* bo = (const float*)d_in[8];
  float* y = (float*)d_out;

  char* ws = (char*)d_ws;
  const size_t WB = (size_t)C_ * C_ * 2;
  const size_t XB = (size_t)B_ * T_ * C_ * 2;
  bf16_t* wqb = (bf16_t*)(ws + 0 * WB);
  bf16_t* wkb = (bf16_t*)(ws + 1 * WB);
  bf16_t* wvb = (bf16_t*)(ws + 2 * WB);
  bf16_t* wob = (bf16_t*)(ws + 3 * WB);
  bf16_t* xt  = (bf16_t*)(ws + 4 * WB);
  bf16_t* qb_ = (bf16_t*)(ws + 4 * WB + 1 * XB);
  bf16_t* kb_ = (bf16_t*)(ws + 4 * WB + 2 * XB);
  bf16_t* vtb = (bf16_t*)(ws + 4 * WB + 3 * XB);
  bf16_t* aob = xt;  // alias: x_t dead after qkv_gemm

  prep<<<dim3(T_ / 32, C_ / 32, B_ + 1), dim3(32, 8), 0, stream>>>(
      x, xt, Wq, Wk, Wv, Wo, wqb, wkb, wvb, wob);
  qkv_gemm<<<dim3(T_ / 128, C_ / 128, B_ * 3), dim3(256), 0, stream>>>(
      wqb, wkb, wvb, bq, bk, bv, xt, qb_, kb_, vtb);
  attn_kernel<<<dim3((T_ / 256) * B_ * NH_), dim3(512), 0, stream>>>(qb_, kb_, vtb, aob);
  out_gemm<<<dim3(T_ / 128, C_ / 128, B_), dim3(256), 0, stream>>>(wob, bo, aob, y);
}